// Round 4
// baseline (109.781 us; speedup 1.0000x reference)
//
#include <hip/hip_runtime.h>
#include <math.h>

// NetVLAD: B=8, N=2048, D=128, K=64, fp32 in/out.
#define BB 8
#define NN 2048
#define DD 128
#define KK 64
#define PP 64            // blocks per batch for K1 (512 blocks = 2/CU)
#define NPB (NN / PP)    // 32 descriptors per block
#define TI 16            // descriptors per tile (2 tiles per block)

// ---------------------------------------------------------------------------
// K1 v4: PP=64, two 16-descriptor tiles per block, double-buffered LDS,
// sumA*c folded into the epilogue (part_sA eliminated).
//   prologue: issue ALL global loads (both tiles' x rows + centroid frags)
//             up front; ||c||^2 reduce overlaps the load latency.
//   per tile tt (unrolled):
//     norm:   4-shfl 16-lane row reduce in registers, write xs[tt]
//     bar     Phase B: 16 dot+exp chains -> e regs; per-wave softmax
//             partial via 3 shfl -> sL[tt][i][wave]
//     bar     Phase C: accumulate assign * xn into register tile
//   epilogue: acc -= sA * c  (exact: e values are pr-replicated, so sA0/sA1
//             are the full block-level sumA), write 16 MB partials.
// vs v3: half the partial traffic, 2x work per block amortizing centroid
// setup + epilogue; same math modulo reassociation of the -sumA*c term.
// ---------------------------------------------------------------------------
__global__ __launch_bounds__(256, 2) void netvlad_k1(
    const float* __restrict__ x, const float* __restrict__ cent,
    float* __restrict__ part_acc)
{
    const int b    = blockIdx.x >> 6;    // / PP
    const int p    = blockIdx.x & 63;    // % PP
    const int t    = threadIdx.x;
    const int kq   = t >> 3;             // 0..31: owns k = {2kq, 2kq+1}
    const int pr   = t & 7;              // 0..7: owns d-range [pr*16, +16)
    const int dbase = pr * 16;
    const int wave = t >> 6;

    __shared__ __align__(16) float xs[2][TI][DD];  // 16 KB: normalized tiles
    __shared__ __align__(16) float sL[2][TI][4];   // per-wave exp-sum partials

    // Rotated chunk offsets: register slot jj -> physical d-chunk
    // ((jj+pr)&3) inside this thread's 16-float range (2-way bank alias max).
    int off[4];
    #pragma unroll
    for (int jj = 0; jj < 4; ++jj) off[jj] = dbase + (((jj + pr) & 3) << 2);

    // ---- issue BOTH tiles' x loads: thread t owns row i0 = t>>4 of each
    // tile, floats [tl*4,+4) and [64+tl*4,+4). Fully coalesced 16B/lane.
    const int i0 = t >> 4, tl = t & 15;
    const float* xb = x + ((size_t)b * NN + (size_t)p * NPB) * DD;
    float4 xv[2][2];
    #pragma unroll
    for (int tt = 0; tt < 2; ++tt) {
        const float* xr = xb + (size_t)(tt * TI + i0) * DD;
        xv[tt][0] = *(const float4*)(xr + tl * 4);
        xv[tt][1] = *(const float4*)(xr + 64 + tl * 4);
    }

    // ---- centroid fragments + ||c_k||^2 (overlaps x-load latency)
    float4 cA[4], cB[4];
    float cn2a = 0.f, cn2b = 0.f;
    #pragma unroll
    for (int jj = 0; jj < 4; ++jj) {
        cA[jj] = *(const float4*)(cent + (2 * kq) * DD + off[jj]);
        cB[jj] = *(const float4*)(cent + (2 * kq + 1) * DD + off[jj]);
        cn2a += cA[jj].x*cA[jj].x + cA[jj].y*cA[jj].y + cA[jj].z*cA[jj].z + cA[jj].w*cA[jj].w;
        cn2b += cB[jj].x*cB[jj].x + cB[jj].y*cB[jj].y + cB[jj].z*cB[jj].z + cB[jj].w*cB[jj].w;
    }
    #pragma unroll
    for (int m = 1; m < 8; m <<= 1) {
        cn2a += __shfl_xor(cn2a, m);
        cn2b += __shfl_xor(cn2b, m);
    }

    float4 acc0[4], acc1[4];
    #pragma unroll
    for (int jj = 0; jj < 4; ++jj) {
        acc0[jj] = make_float4(0.f, 0.f, 0.f, 0.f);
        acc1[jj] = make_float4(0.f, 0.f, 0.f, 0.f);
    }
    float sA0 = 0.f, sA1 = 0.f;

    #pragma unroll
    for (int tt = 0; tt < 2; ++tt) {
        // ---- normalize row i0 of tile tt in registers, write xs[tt] once.
        {
            float4 v0 = xv[tt][0], v1 = xv[tt][1];
            float ss = v0.x*v0.x + v0.y*v0.y + v0.z*v0.z + v0.w*v0.w
                     + v1.x*v1.x + v1.y*v1.y + v1.z*v1.z + v1.w*v1.w;
            #pragma unroll
            for (int m = 1; m < 16; m <<= 1) ss += __shfl_xor(ss, m);
            const float rn = 1.0f / fmaxf(sqrtf(ss), 1e-12f);
            v0.x *= rn; v0.y *= rn; v0.z *= rn; v0.w *= rn;
            v1.x *= rn; v1.y *= rn; v1.z *= rn; v1.w *= rn;
            *(float4*)(&xs[tt][i0][tl * 4])      = v0;
            *(float4*)(&xs[tt][i0][64 + tl * 4]) = v1;
        }
        __syncthreads();   // xs[tt] tile visible (dbuf: no race with prev C)

        // ---- Phase B: dots + exp.  assign ∝ exp(||c||^2 - 2 xn·c)
        float e0[TI], e1[TI];
        #pragma unroll
        for (int i = 0; i < TI; ++i) {
            float S0 = 0.f, S1 = 0.f;
            #pragma unroll
            for (int jj = 0; jj < 4; ++jj) {
                float4 v = *(const float4*)(&xs[tt][i][off[jj]]);
                S0 += v.x*cA[jj].x + v.y*cA[jj].y + v.z*cA[jj].z + v.w*cA[jj].w;
                S1 += v.x*cB[jj].x + v.y*cB[jj].y + v.z*cB[jj].z + v.w*cB[jj].w;
            }
            #pragma unroll
            for (int m = 1; m < 8; m <<= 1) {   // reduce across the 8 d-parts
                S0 += __shfl_xor(S0, m);
                S1 += __shfl_xor(S1, m);
            }
            e0[i] = __expf(cn2a - 2.f * S0);
            e1[i] = __expf(cn2b - 2.f * S1);
            // per-wave softmax partial: sum this wave's 16 k's
            float es = e0[i] + e1[i];
            #pragma unroll
            for (int m = 8; m < 64; m <<= 1) es += __shfl_xor(es, m);
            if ((t & 63) == 0) sL[tt][i][wave] = es;
        }
        __syncthreads();   // sL[tt] complete

        // ---- Phase C: accumulate assign * xn into register tile
        #pragma unroll
        for (int i = 0; i < TI; ++i) {
            const float4 s4 = *(const float4*)(&sL[tt][i][0]);   // broadcast
            const float rs = 1.0f / (s4.x + s4.y + s4.z + s4.w);
            const float a0 = e0[i] * rs, a1 = e1[i] * rs;
            sA0 += a0; sA1 += a1;
            #pragma unroll
            for (int jj = 0; jj < 4; ++jj) {
                float4 v = *(const float4*)(&xs[tt][i][off[jj]]);
                acc0[jj].x += a0*v.x; acc0[jj].y += a0*v.y; acc0[jj].z += a0*v.z; acc0[jj].w += a0*v.w;
                acc1[jj].x += a1*v.x; acc1[jj].y += a1*v.y; acc1[jj].z += a1*v.z; acc1[jj].w += a1*v.w;
            }
        }
    }

    // ---- epilogue: fold -sumA*c here (e values are pr-replicated, so
    // sA0/sA1 are the full block sums), then write partials.
    const size_t base = (size_t)(b * PP + p) * KK * DD;
    #pragma unroll
    for (int jj = 0; jj < 4; ++jj) {
        acc0[jj].x -= sA0 * cA[jj].x; acc0[jj].y -= sA0 * cA[jj].y;
        acc0[jj].z -= sA0 * cA[jj].z; acc0[jj].w -= sA0 * cA[jj].w;
        acc1[jj].x -= sA1 * cB[jj].x; acc1[jj].y -= sA1 * cB[jj].y;
        acc1[jj].z -= sA1 * cB[jj].z; acc1[jj].w -= sA1 * cB[jj].w;
        *(float4*)(part_acc + base + (2 * kq) * DD + off[jj])     = acc0[jj];
        *(float4*)(part_acc + base + (2 * kq + 1) * DD + off[jj]) = acc1[jj];
    }
}

// ---------------------------------------------------------------------------
// K2 v4: sum 64 partials per (b,k), intra-normalize, apply global factor
// (sqrt(K)=8 folded as 0.125). The -sumA*c subtraction already happened in
// K1. Grid: BB*KK = 512 blocks of 256 threads; 8-deep load chains.
// ---------------------------------------------------------------------------
__global__ __launch_bounds__(256) void netvlad_k2(
    const float* __restrict__ part_acc, float* __restrict__ out)
{
    const int b  = blockIdx.x >> 6;
    const int k  = blockIdx.x & 63;
    const int t  = threadIdx.x;
    const int d4 = t & 31;               // float4 column 0..31
    const int ps = t >> 5;               // p-slice 0..7

    // each thread sums 8 p's for its float4 column (independent loads)
    float4 acc = make_float4(0.f, 0.f, 0.f, 0.f);
    const float* base = part_acc + ((size_t)(b * PP) * KK + k) * DD + d4 * 4;
    #pragma unroll
    for (int pp = 0; pp < 8; ++pp) {
        const float4 v = *(const float4*)(base + (size_t)(pp * 8 + ps) * KK * DD);
        acc.x += v.x; acc.y += v.y; acc.z += v.z; acc.w += v.w;
    }

    __shared__ __align__(16) float4 red[8][32];
    red[ps][d4] = acc;
    __syncthreads();

    if (t < 32) {
        float4 v = red[0][t];
        #pragma unroll
        for (int s = 1; s < 8; ++s) {
            v.x += red[s][t].x; v.y += red[s][t].y;
            v.z += red[s][t].z; v.w += red[s][t].w;
        }
        float ss = v.x*v.x + v.y*v.y + v.z*v.z + v.w*v.w;
        #pragma unroll
        for (int m = 1; m < 32; m <<= 1) ss += __shfl_xor(ss, m);
        const float rn = 0.125f / fmaxf(sqrtf(ss), 1e-12f);
        v.x *= rn; v.y *= rn; v.z *= rn; v.w *= rn;
        *(float4*)(out + ((size_t)b * KK + k) * DD + t * 4) = v;
    }
}

extern "C" void kernel_launch(void* const* d_in, const int* in_sizes, int n_in,
                              void* d_out, int out_size, void* d_ws, size_t ws_size,
                              hipStream_t stream) {
    const float* x    = (const float*)d_in[0];   // [8, 2048, 128] fp32
    const float* cent = (const float*)d_in[1];   // [64, 128] fp32
    float* out = (float*)d_out;                  // [8, 8192] fp32

    float* part_acc = (float*)d_ws;              // 8*64*64*128 fp32 = 16 MB

    netvlad_k1<<<dim3(BB * PP), dim3(256), 0, stream>>>(x, cent, part_acc);
    netvlad_k2<<<dim3(BB * KK), dim3(256), 0, stream>>>(part_acc, out);
}